// Round 1
// baseline (801.364 us; speedup 1.0000x reference)
//
#include <hip/hip_runtime.h>

#define EPSF 1e-6f

constexpr int Bd = 16, Nd = 1024, Ed = 256, Fd = 256;
constexpr int Rr = 3 * Ed; // 768 rows of the stacked [a;b;c] operand

// ---------------------------------------------------------------------------
// prep: Mt[r][f] = {A,Bw,Cw}[f][e] with r = t*256+e  (768x256, coalesced reads
// for the GEMM), Wt[f][g] = W[g][f] (256x256).
// grid = 768 blocks x 256 threads; r == blockIdx.x, f == threadIdx.x
// ---------------------------------------------------------------------------
__global__ __launch_bounds__(256) void prep_kernel(
    const float* __restrict__ A, const float* __restrict__ Bw,
    const float* __restrict__ Cw, const float* __restrict__ W,
    float* __restrict__ Mt, float* __restrict__ Wt)
{
    int r = blockIdx.x;
    int f = threadIdx.x;
    const float* src = (r < 256) ? A : (r < 512) ? Bw : Cw;
    int e = r & 255;
    Mt[r * Fd + f] = src[f * Ed + e];
    if (r < Fd) Wt[r * Fd + f] = W[f * Fd + r]; // Wt[f_][g] = W[g][f_]
}

// ---------------------------------------------------------------------------
// stage1: fused basis + terms + GEMM1.
// One block per (b, group of 4 n).  LDS slab[r][q][k] (k padded to 4) holds the
// stacked a/b/c terms for 4 columns; each thread f then accumulates
// Y[b,n,f,i] = sum_r Mt[r][f] * slab[r][q][i].
// ---------------------------------------------------------------------------
__global__ __launch_bounds__(256) void stage1_kernel(
    const float* __restrict__ X, const float* __restrict__ Jp,
    const float* __restrict__ Mt, float* __restrict__ Y)
{
    __shared__ __align__(16) float slab[Rr * 16]; // 48 KB
    int b   = blockIdx.x >> 8;
    int n0  = (blockIdx.x & 255) * 4;
    int tid = threadIdx.x;

    #pragma unroll
    for (int q = 0; q < 4; ++q) {
        int n = n0 + q;
        int base = ((b * Nd + n) * Ed + tid) * 3;
        float x0 = X[base + 0], x1 = X[base + 1], x2 = X[base + 2];
        float j0 = Jp[base + 0], j1 = Jp[base + 1], j2 = Jp[base + 2];

        float nrm = sqrtf(j0 * j0 + j1 * j1 + j2 * j2) + EPSF;
        float nj0 = j0 / nrm, nj1 = j1 / nrm, nj2 = j2 / nrm;
        float s2 = nj0 * nj0 + nj1 * nj1;
        float uz = -s2 / (nj2 + EPSF);
        float un = sqrtf(s2 + uz * uz) + EPSF;
        float u0 = nj0 / un, u1 = nj1 / un, u2 = uz / un;
        // V = cross(U, nJ)
        float v0 = u1 * nj2 - u2 * nj1;
        float v1 = u2 * nj0 - u0 * nj2;
        float v2 = u0 * nj1 - u1 * nj0;
        // RtX[i] = U[i]*X0 + V[i]*X1 + nJ[i]*X2
        float r0 = u0 * x0 + v0 * x1 + nj0 * x2;
        float r1 = u1 * x0 + v1 * x1 + nj1 * x2;
        float r2 = u2 * x0 + v2 * x1 + nj2 * x2;

        // a[k] = R[k,0]*r0 + R[k,1]*r1 ; rows of R are U, V, nJ
        float* s = &slab[tid * 16 + q * 4];
        s[0] = u0 * r0 + u1 * r1;
        s[1] = v0 * r0 + v1 * r1;
        s[2] = nj0 * r0 + nj1 * r1;
        // b[k] = R[k,1]*r0 - R[k,0]*r1
        s = &slab[(Ed + tid) * 16 + q * 4];
        s[0] = u1 * r0 - u0 * r1;
        s[1] = v1 * r0 - v0 * r1;
        s[2] = nj1 * r0 - nj0 * r1;
        // c[k] = R[k,2]*r2
        s = &slab[(2 * Ed + tid) * 16 + q * 4];
        s[0] = u2 * r2;
        s[1] = v2 * r2;
        s[2] = nj2 * r2;
    }
    __syncthreads();

    float acc[4][3] = {};
    const float4* slab4 = (const float4*)slab;
    const float* mp = Mt + tid;
    #pragma unroll 4
    for (int r = 0; r < Rr; ++r) {
        float m = mp[r * Fd];               // coalesced, L2-resident
        #pragma unroll
        for (int q = 0; q < 4; ++q) {
            float4 s = slab4[r * 4 + q];    // uniform address -> broadcast
            acc[q][0] = fmaf(m, s.x, acc[q][0]);
            acc[q][1] = fmaf(m, s.y, acc[q][1]);
            acc[q][2] = fmaf(m, s.z, acc[q][2]);
        }
    }

    #pragma unroll
    for (int q = 0; q < 4; ++q) {
        int yb = ((b * Nd + n0 + q) * Fd + tid) * 3;
        Y[yb + 0] = acc[q][0];
        Y[yb + 1] = acc[q][1];
        Y[yb + 2] = acc[q][2];
    }
}

// ---------------------------------------------------------------------------
// stage2: d = W @ x (per b) + VN leaky-relu epilogue.
// One block per (b, tile of 16 n).  x tile staged in LDS as xl[f][i][16];
// thread g accumulates d[g,i,j] over f, then applies the epilogue and writes
// out[b,g,i,n0+j] (64B-contiguous runs along n per (g,i)).
// ---------------------------------------------------------------------------
__global__ __launch_bounds__(256) void stage2_kernel(
    const float* __restrict__ Y, const float* __restrict__ Wt,
    float* __restrict__ out)
{
    __shared__ __align__(16) float xl[Fd * 48]; // 48 KB
    int b   = blockIdx.x >> 6;
    int n0  = (blockIdx.x & 63) * 16;
    int tid = threadIdx.x;

    #pragma unroll
    for (int j = 0; j < 16; ++j) {
        int base = ((b * Nd + n0 + j) * Fd + tid) * 3; // coalesced 12B/thread
        xl[tid * 48 + j]      = Y[base + 0];
        xl[tid * 48 + 16 + j] = Y[base + 1];
        xl[tid * 48 + 32 + j] = Y[base + 2];
    }
    __syncthreads();

    float acc[48] = {}; // [i*16 + j]
    const float4* xl4 = (const float4*)xl;
    const float* wp = Wt + tid;
    #pragma unroll 2
    for (int f = 0; f < Fd; ++f) {
        float w = wp[f * Fd];               // coalesced, L2-resident
        #pragma unroll
        for (int v = 0; v < 12; ++v) {
            float4 s = xl4[f * 12 + v];     // uniform address -> broadcast
            acc[v * 4 + 0] = fmaf(w, s.x, acc[v * 4 + 0]);
            acc[v * 4 + 1] = fmaf(w, s.y, acc[v * 4 + 1]);
            acc[v * 4 + 2] = fmaf(w, s.z, acc[v * 4 + 2]);
            acc[v * 4 + 3] = fmaf(w, s.w, acc[v * 4 + 3]);
        }
    }

    int gb = ((b * Fd + tid) * 3) * Nd + n0;
    #pragma unroll
    for (int j = 0; j < 16; ++j) {
        float x0 = xl[tid * 48 + j];
        float x1 = xl[tid * 48 + 16 + j];
        float x2 = xl[tid * 48 + 32 + j];
        float d0 = acc[j], d1 = acc[16 + j], d2 = acc[32 + j];
        float dot = x0 * d0 + x1 * d1 + x2 * d2;
        float dn  = d0 * d0 + d1 * d1 + d2 * d2;
        float sc  = dot / (dn + EPSF);
        bool pos  = dot >= 0.0f;
        float l0 = pos ? x0 : fmaf(-sc, d0, x0);
        float l1 = pos ? x1 : fmaf(-sc, d1, x1);
        float l2 = pos ? x2 : fmaf(-sc, d2, x2);
        out[gb + j]          = fmaf(0.8f, l0, 0.2f * x0);
        out[gb + Nd + j]     = fmaf(0.8f, l1, 0.2f * x1);
        out[gb + 2 * Nd + j] = fmaf(0.8f, l2, 0.2f * x2);
    }
}

extern "C" void kernel_launch(void* const* d_in, const int* in_sizes, int n_in,
                              void* d_out, int out_size, void* d_ws, size_t ws_size,
                              hipStream_t stream)
{
    const float* X  = (const float*)d_in[0];
    const float* J  = (const float*)d_in[1];
    const float* A  = (const float*)d_in[2];
    const float* Bw = (const float*)d_in[3];
    const float* Cw = (const float*)d_in[4];
    const float* W  = (const float*)d_in[5];
    float* out = (float*)d_out;

    char* ws = (char*)d_ws;
    float* Mt = (float*)ws;                            // 768*256*4   = 786432 B
    float* Wt = (float*)(ws + 786432);                 // 256*256*4   = 262144 B
    float* Y  = (float*)(ws + 786432 + 262144);        // 16*1024*256*3*4 = 50331648 B

    hipLaunchKernelGGL(prep_kernel,  dim3(Rr),            dim3(256), 0, stream,
                       A, Bw, Cw, W, Mt, Wt);
    hipLaunchKernelGGL(stage1_kernel, dim3(Bd * (Nd / 4)), dim3(256), 0, stream,
                       X, J, Mt, Y);
    hipLaunchKernelGGL(stage2_kernel, dim3(Bd * (Nd / 16)), dim3(256), 0, stream,
                       Y, Wt, out);
}

// Round 3
// 158.445 us; speedup vs baseline: 5.0577x; 5.0577x over previous
//
#include <hip/hip_runtime.h>

typedef __attribute__((ext_vector_type(8))) short short8;
typedef __attribute__((ext_vector_type(4))) float f32x4;
typedef __attribute__((ext_vector_type(2))) unsigned uint2v;

#define EPSF 1e-6f
constexpr int Nd = 1024;

__device__ __forceinline__ unsigned short f2bf(float f) {
    unsigned u = __float_as_uint(f);
    u += 0x7fff + ((u >> 16) & 1);          // RNE
    return (unsigned short)(u >> 16);
}
__device__ __forceinline__ float bf2f(unsigned short h) {
    return __uint_as_float(((unsigned)h) << 16);
}
__device__ __forceinline__ void glds16(const void* g, void* l) {
    __builtin_amdgcn_global_load_lds(
        (const __attribute__((address_space(1))) unsigned*)g,
        (__attribute__((address_space(3))) unsigned*)l, 16, 0, 0);
}

// ---------------------------------------------------------------------------
// prep: hi/lo bf16 split of stacked [A|Bw|Cw] (Mhi/Mlo[f][768], K-contig) and
// of W (Whi/Wlo[g][256]).  grid 256 x 256.
// ---------------------------------------------------------------------------
__global__ __launch_bounds__(256) void prep_kernel(
    const float* __restrict__ A, const float* __restrict__ Bw,
    const float* __restrict__ Cw, const float* __restrict__ W,
    unsigned short* __restrict__ Mhi, unsigned short* __restrict__ Mlo,
    unsigned short* __restrict__ Whi, unsigned short* __restrict__ Wlo)
{
    int f = blockIdx.x, e = threadIdx.x;
    float vals[3] = { A[f * 256 + e], Bw[f * 256 + e], Cw[f * 256 + e] };
    #pragma unroll
    for (int t = 0; t < 3; ++t) {
        float v = vals[t];
        unsigned short h = f2bf(v);
        Mhi[f * 768 + t * 256 + e] = h;
        Mlo[f * 768 + t * 256 + e] = f2bf(v - bf2f(h));
    }
    float w = W[f * 256 + e];
    unsigned short h = f2bf(w);
    Whi[f * 256 + e] = h;
    Wlo[f * 256 + e] = f2bf(w - bf2f(h));
}

// ---------------------------------------------------------------------------
// tgen: basis + terms in f32, store hi/lo bf16 Tt[b_loc][c][r], c=i*1024+n,
// r=t*256+e.  grid nb*1024 x 256 (thread = e).
// ---------------------------------------------------------------------------
__global__ __launch_bounds__(256) void tgen_kernel(
    const float* __restrict__ X, const float* __restrict__ Jp,
    unsigned short* __restrict__ Thi, unsigned short* __restrict__ Tlo, int b_off)
{
    int b_loc = blockIdx.x >> 10;
    int n     = blockIdx.x & 1023;
    int e     = threadIdx.x;
    int b_g   = b_off + b_loc;

    size_t base = ((size_t)(b_g * Nd + n) * 256 + e) * 3;
    float x0 = X[base], x1 = X[base + 1], x2 = X[base + 2];
    float j0 = Jp[base], j1 = Jp[base + 1], j2 = Jp[base + 2];

    float nrm = sqrtf(j0 * j0 + j1 * j1 + j2 * j2) + EPSF;
    float nj0 = j0 / nrm, nj1 = j1 / nrm, nj2 = j2 / nrm;
    float s2 = nj0 * nj0 + nj1 * nj1;
    float uz = -s2 / (nj2 + EPSF);
    float un = sqrtf(s2 + uz * uz) + EPSF;
    float u0 = nj0 / un, u1 = nj1 / un, u2 = uz / un;
    float v0 = u1 * nj2 - u2 * nj1;
    float v1 = u2 * nj0 - u0 * nj2;
    float v2 = u0 * nj1 - u1 * nj0;
    float r0 = u0 * x0 + v0 * x1 + nj0 * x2;
    float r1 = u1 * x0 + v1 * x1 + nj1 * x2;
    float r2 = u2 * x0 + v2 * x1 + nj2 * x2;

    float ta[3], tb[3], tc[3];
    ta[0] = u0 * r0 + u1 * r1;   tb[0] = u1 * r0 - u0 * r1;   tc[0] = u2 * r2;
    ta[1] = v0 * r0 + v1 * r1;   tb[1] = v1 * r0 - v0 * r1;   tc[1] = v2 * r2;
    ta[2] = nj0 * r0 + nj1 * r1; tb[2] = nj1 * r0 - nj0 * r1; tc[2] = nj2 * r2;

    size_t rb = ((size_t)b_loc * 3072 + n) * 768 + e;
    #pragma unroll
    for (int i = 0; i < 3; ++i) {
        size_t r = rb + (size_t)i * 1024 * 768;
        float t3[3] = { ta[i], tb[i], tc[i] };
        #pragma unroll
        for (int t = 0; t < 3; ++t) {
            unsigned short h = f2bf(t3[t]);
            Thi[r + t * 256] = h;
            Tlo[r + t * 256] = f2bf(t3[t] - bf2f(h));
        }
    }
}

// ---------------------------------------------------------------------------
// gemm1: per b, Y[c][f] = sum_r M[f][r] * T[c][r], hi/lo bf16 3-pass MFMA.
// 128f x 128c tile, 4 waves (2x2), K=768, BK=32, double-buffered
// global_load_lds with pre-swizzled source.  Output hi/lo bf16 (K-contig for
// gemm2).  grid: nb*48.
// ---------------------------------------------------------------------------
__global__ __launch_bounds__(256) void gemm1_kernel(
    const unsigned short* __restrict__ Mhi, const unsigned short* __restrict__ Mlo,
    const unsigned short* __restrict__ Thi, const unsigned short* __restrict__ Tlo,
    unsigned short* __restrict__ Yhi, unsigned short* __restrict__ Ylo)
{
    __shared__ char lds[65536];
    int tid = threadIdx.x;
    int bid = blockIdx.x;
    int b   = bid / 48;
    int rt  = bid % 48;
    int f0  = (rt / 24) * 128;
    int c0  = (rt % 24) * 128;
    size_t bC    = (size_t)b * 3072;
    size_t Tbase = (bC + c0) * 768;

    auto stage = [&](int buf, int kt) {
        char* lah = lds + buf * 32768;
        char* lal = lah + 8192;
        char* lbh = lah + 16384;
        char* lbl = lah + 24576;
        int k0 = kt * 32;
        int wv = (tid >> 6) * 1024;
        #pragma unroll
        for (int h = 0; h < 2; ++h) {
            int m = h * 256 + tid;
            int row = m >> 2, slot = m & 3;
            unsigned sw = (slot * 16) ^ ((row & 3) << 4);
            size_t goA = ((size_t)(f0 + row) * 768 + k0) * 2 + sw;
            size_t goB = (Tbase + (size_t)row * 768 + k0) * 2 + sw;
            glds16((const char*)Mhi + goA, lah + h * 4096 + wv);
            glds16((const char*)Mlo + goA, lal + h * 4096 + wv);
            glds16((const char*)Thi + goB, lbh + h * 4096 + wv);
            glds16((const char*)Tlo + goB, lbl + h * 4096 + wv);
        }
    };

    int l = tid & 63, lr = l & 15, lq = l >> 4;
    int w = tid >> 6, wf = w >> 1, wc = w & 1;

    f32x4 acc[4][4] = {};
    stage(0, 0);
    __syncthreads();

    for (int kt = 0; kt < 24; ++kt) {
        int cur = kt & 1;
        if (kt < 23) stage(cur ^ 1, kt + 1);
        const char* lah = lds + cur * 32768;
        const char* lal = lah + 8192;
        const char* lbh = lah + 16384;
        const char* lbl = lah + 24576;
        short8 afh[4], afl[4], bfh[4], bfl[4];
        #pragma unroll
        for (int m = 0; m < 4; ++m) {
            int R = wf * 64 + m * 16 + lr;
            unsigned off = R * 64 + ((lq * 16) ^ ((R & 3) << 4));
            afh[m] = *(const short8*)(lah + off);
            afl[m] = *(const short8*)(lal + off);
        }
        #pragma unroll
        for (int n = 0; n < 4; ++n) {
            int R = wc * 64 + n * 16 + lr;
            unsigned off = R * 64 + ((lq * 16) ^ ((R & 3) << 4));
            bfh[n] = *(const short8*)(lbh + off);
            bfl[n] = *(const short8*)(lbl + off);
        }
        #pragma unroll
        for (int m = 0; m < 4; ++m)
            #pragma unroll
            for (int n = 0; n < 4; ++n) {
                acc[m][n] = __builtin_amdgcn_mfma_f32_16x16x32_bf16(afh[m], bfh[n], acc[m][n], 0, 0, 0);
                acc[m][n] = __builtin_amdgcn_mfma_f32_16x16x32_bf16(afh[m], bfl[n], acc[m][n], 0, 0, 0);
                acc[m][n] = __builtin_amdgcn_mfma_f32_16x16x32_bf16(afl[m], bfh[n], acc[m][n], 0, 0, 0);
            }
        __syncthreads();
    }

    // D: row=f (lq*4+reg), col=c (lr) -> store Y[c][f] hi/lo
    #pragma unroll
    for (int n = 0; n < 4; ++n) {
        int c = c0 + wc * 64 + n * 16 + lr;
        size_t rowb = (bC + c) * 256;
        #pragma unroll
        for (int m = 0; m < 4; ++m) {
            int fb = f0 + wf * 64 + m * 16 + lq * 4;
            f32x4 v = acc[m][n];
            unsigned short h0 = f2bf(v[0]), h1 = f2bf(v[1]),
                           h2 = f2bf(v[2]), h3 = f2bf(v[3]);
            uint2v ph, pl;
            ph.x = (unsigned)h0 | ((unsigned)h1 << 16);
            ph.y = (unsigned)h2 | ((unsigned)h3 << 16);
            pl.x = (unsigned)f2bf(v[0] - bf2f(h0)) | ((unsigned)f2bf(v[1] - bf2f(h1)) << 16);
            pl.y = (unsigned)f2bf(v[2] - bf2f(h2)) | ((unsigned)f2bf(v[3] - bf2f(h3)) << 16);
            *(uint2v*)(Yhi + rowb + fb) = ph;
            *(uint2v*)(Ylo + rowb + fb) = pl;
        }
    }
}

// ---------------------------------------------------------------------------
// gemm2: per b, D[c][g] = sum_f Y[c][f] * W[g][f], hi/lo 3-pass; epilogue =
// VN leaky relu in f32.  Block tile 192c (3i x 64n) x 64g, 4 waves
// (2 n-halves x 2 g-halves), K=256, BK=32.  grid: nb*64.
// ---------------------------------------------------------------------------
__global__ __launch_bounds__(256) void gemm2_kernel(
    const unsigned short* __restrict__ Whi, const unsigned short* __restrict__ Wlo,
    const unsigned short* __restrict__ Yhi, const unsigned short* __restrict__ Ylo,
    float* __restrict__ out, int b_off)
{
    __shared__ char lds[65536];
    int tid = threadIdx.x;
    int bid = blockIdx.x;
    int b   = bid / 64;           // chunk-local b
    int rt  = bid % 64;
    int g0  = (rt / 16) * 64;
    int n0  = (rt % 16) * 64;
    size_t bC = (size_t)b * 3072;

    auto stage = [&](int buf, int kt) {
        char* lah = lds + buf * 32768;  // A=Y tile 192x32 hi: 12KB
        char* lal = lah + 12288;        // A lo: 12KB
        char* lbh = lah + 24576;        // B=W tile 64x32 hi: 4KB
        char* lbl = lah + 28672;        // B lo: 4KB
        int k0 = kt * 32;
        int wv = (tid >> 6) * 1024;
        #pragma unroll
        for (int h = 0; h < 3; ++h) {
            int m = h * 256 + tid;
            int rc = m >> 2, slot = m & 3;
            int cg = (rc >> 6) * 1024 + n0 + (rc & 63);
            unsigned sw = (slot * 16) ^ ((rc & 3) << 4);
            size_t go = ((bC + cg) * 256 + k0) * 2 + sw;
            glds16((const char*)Yhi + go, lah + h * 4096 + wv);
            glds16((const char*)Ylo + go, lal + h * 4096 + wv);
        }
        {
            int row = tid >> 2, slot = tid & 3;
            unsigned sw = (slot * 16) ^ ((row & 3) << 4);
            size_t go = ((size_t)(g0 + row) * 256 + k0) * 2 + sw;
            glds16((const char*)Whi + go, lbh + wv);
            glds16((const char*)Wlo + go, lbl + wv);
        }
    };

    int l = tid & 63, lr = l & 15, lq = l >> 4;
    int w = tid >> 6, wn = w & 1, wg = w >> 1;

    f32x4 acc[3][2][2] = {};
    stage(0, 0);
    __syncthreads();

    for (int kt = 0; kt < 8; ++kt) {
        int cur = kt & 1;
        if (kt < 7) stage(cur ^ 1, kt + 1);
        const char* lah = lds + cur * 32768;
        const char* lal = lah + 12288;
        const char* lbh = lah + 24576;
        const char* lbl = lah + 28672;
        short8 afh[3][2], afl[3][2], bgh[2], bgl[2];
        #pragma unroll
        for (int i = 0; i < 3; ++i)
            #pragma unroll
            for (int nc = 0; nc < 2; ++nc) {
                int R = i * 64 + wn * 32 + nc * 16 + lr;
                unsigned off = R * 64 + ((lq * 16) ^ ((R & 3) << 4));
                afh[i][nc] = *(const short8*)(lah + off);
                afl[i][nc] = *(const short8*)(lal + off);
            }
        #pragma unroll
        for (int gf = 0; gf < 2; ++gf) {
            int R = wg * 32 + gf * 16 + lr;
            unsigned off = R * 64 + ((lq * 16) ^ ((R & 3) << 4));
            bgh[gf] = *(const short8*)(lbh + off);
            bgl[gf] = *(const short8*)(lbl + off);
        }
        #pragma unroll
        for (int i = 0; i < 3; ++i)
            #pragma unroll
            for (int nc = 0; nc < 2; ++nc)
                #pragma unroll
                for (int gf = 0; gf < 2; ++gf) {
                    acc[i][nc][gf] = __builtin_amdgcn_mfma_f32_16x16x32_bf16(afh[i][nc], bgh[gf], acc[i][nc][gf], 0, 0, 0);
                    acc[i][nc][gf] = __builtin_amdgcn_mfma_f32_16x16x32_bf16(afh[i][nc], bgl[gf], acc[i][nc][gf], 0, 0, 0);
                    acc[i][nc][gf] = __builtin_amdgcn_mfma_f32_16x16x32_bf16(afl[i][nc], bgh[gf], acc[i][nc][gf], 0, 0, 0);
                }
        __syncthreads();
    }

    // epilogue; D: row=c (n = nb+reg at fixed i), col=g (lr)
    int b_g = b_off + b;
    #pragma unroll
    for (int nc = 0; nc < 2; ++nc)
        #pragma unroll
        for (int gf = 0; gf < 2; ++gf) {
            int g  = g0 + wg * 32 + gf * 16 + lr;
            int nb = n0 + wn * 32 + nc * 16 + lq * 4;
            float x[3][4];
            #pragma unroll
            for (int i = 0; i < 3; ++i)
                #pragma unroll
                for (int r = 0; r < 4; ++r) {
                    size_t idx = (bC + i * 1024 + nb + r) * 256 + g;
                    x[i][r] = bf2f(Yhi[idx]) + bf2f(Ylo[idx]);
                }
            f32x4 o[3];
            #pragma unroll
            for (int r = 0; r < 4; ++r) {
                float d0 = acc[0][nc][gf][r], d1 = acc[1][nc][gf][r], d2 = acc[2][nc][gf][r];
                float dot = x[0][r] * d0 + x[1][r] * d1 + x[2][r] * d2;
                float dn  = d0 * d0 + d1 * d1 + d2 * d2;
                float sc  = dot / (dn + EPSF);
                bool pos  = dot >= 0.0f;
                float l0 = pos ? x[0][r] : fmaf(-sc, d0, x[0][r]);
                float l1 = pos ? x[1][r] : fmaf(-sc, d1, x[1][r]);
                float l2 = pos ? x[2][r] : fmaf(-sc, d2, x[2][r]);
                o[0][r] = fmaf(0.8f, l0, 0.2f * x[0][r]);
                o[1][r] = fmaf(0.8f, l1, 0.2f * x[1][r]);
                o[2][r] = fmaf(0.8f, l2, 0.2f * x[2][r]);
            }
            #pragma unroll
            for (int i = 0; i < 3; ++i)
                *(f32x4*)(out + ((size_t)(b_g * 256 + g) * 3 + i) * 1024 + nb) = o[i];
        }
}

extern "C" void kernel_launch(void* const* d_in, const int* in_sizes, int n_in,
                              void* d_out, int out_size, void* d_ws, size_t ws_size,
                              hipStream_t stream)
{
    const float* X  = (const float*)d_in[0];
    const float* J  = (const float*)d_in[1];
    const float* A  = (const float*)d_in[2];
    const float* Bw = (const float*)d_in[3];
    const float* Cw = (const float*)d_in[4];
    const float* W  = (const float*)d_in[5];
    float* out = (float*)d_out;

    char* ws = (char*)d_ws;
    unsigned short* Mhi = (unsigned short*)ws;
    unsigned short* Mlo = (unsigned short*)(ws + 393216);
    unsigned short* Whi = (unsigned short*)(ws + 786432);
    unsigned short* Wlo = (unsigned short*)(ws + 917504);
    char* dyn = ws + 1048576;

    hipLaunchKernelGGL(prep_kernel, dim3(256), dim3(256), 0, stream,
                       A, Bw, Cw, W, Mhi, Mlo, Whi, Wlo);

    auto need = [](int nb) {
        return (size_t)1048576 + 2 * ((size_t)nb * 3072 * 768 * 2)
                               + 2 * ((size_t)nb * 3072 * 256 * 2);
    };
    int nb = (ws_size >= need(16)) ? 16 : (ws_size >= need(8)) ? 8 : 4;
    size_t TT = (size_t)nb * 3072 * 768 * 2;
    size_t YB = (size_t)nb * 3072 * 256 * 2;
    unsigned short* Thi = (unsigned short*)dyn;
    unsigned short* Tlo = (unsigned short*)(dyn + TT);
    unsigned short* Yhi = (unsigned short*)(dyn + 2 * TT);
    unsigned short* Ylo = (unsigned short*)(dyn + 2 * TT + YB);

    for (int b0 = 0; b0 < 16; b0 += nb) {
        hipLaunchKernelGGL(tgen_kernel,  dim3(nb * 1024), dim3(256), 0, stream,
                           X, J, Thi, Tlo, b0);
        hipLaunchKernelGGL(gemm1_kernel, dim3(nb * 48),   dim3(256), 0, stream,
                           Mhi, Mlo, Thi, Tlo, Yhi, Ylo);
        hipLaunchKernelGGL(gemm2_kernel, dim3(nb * 64),   dim3(256), 0, stream,
                           Whi, Wlo, Yhi, Ylo, out, b0);
    }
}

// Round 4
// 89.141 us; speedup vs baseline: 8.9898x; 1.7775x over previous
//
#include <hip/hip_runtime.h>

typedef __attribute__((ext_vector_type(8))) _Float16 half8;
typedef __attribute__((ext_vector_type(4))) _Float16 half4v;
typedef __attribute__((ext_vector_type(4))) float f32x4;

#define EPSF 1e-6f
constexpr int Nd = 1024;

__device__ __forceinline__ void glds16(const void* g, void* l) {
    __builtin_amdgcn_global_load_lds(
        (const __attribute__((address_space(1))) unsigned*)g,
        (__attribute__((address_space(3))) unsigned*)l, 16, 0, 0);
}

// ---------------------------------------------------------------------------
// prep: Mh[f][768] = fp16 of stacked [A|Bw|Cw] (K-contig); Wh[g][256] = fp16(W).
// grid 256 x 256.
// ---------------------------------------------------------------------------
__global__ __launch_bounds__(256) void prep_kernel(
    const float* __restrict__ A, const float* __restrict__ Bw,
    const float* __restrict__ Cw, const float* __restrict__ W,
    _Float16* __restrict__ Mh, _Float16* __restrict__ Wh)
{
    int f = blockIdx.x, e = threadIdx.x;
    Mh[f * 768 + e]       = (_Float16)A[f * 256 + e];
    Mh[f * 768 + 256 + e] = (_Float16)Bw[f * 256 + e];
    Mh[f * 768 + 512 + e] = (_Float16)Cw[f * 256 + e];
    Wh[f * 256 + e]       = (_Float16)W[f * 256 + e];
}

// ---------------------------------------------------------------------------
// tgen: basis + terms in f32, store fp16 T[b_loc][c][r], c=i*1024+n, r=t*256+e.
// grid nb*1024 x 256 (thread = e).
// ---------------------------------------------------------------------------
__global__ __launch_bounds__(256) void tgen_kernel(
    const float* __restrict__ X, const float* __restrict__ Jp,
    _Float16* __restrict__ T, int b_off)
{
    int b_loc = blockIdx.x >> 10;
    int n     = blockIdx.x & 1023;
    int e     = threadIdx.x;
    int b_g   = b_off + b_loc;

    size_t base = ((size_t)(b_g * Nd + n) * 256 + e) * 3;
    float x0 = X[base], x1 = X[base + 1], x2 = X[base + 2];
    float j0 = Jp[base], j1 = Jp[base + 1], j2 = Jp[base + 2];

    float nrm = sqrtf(j0 * j0 + j1 * j1 + j2 * j2) + EPSF;
    float nj0 = j0 / nrm, nj1 = j1 / nrm, nj2 = j2 / nrm;
    float s2 = nj0 * nj0 + nj1 * nj1;
    float uz = -s2 / (nj2 + EPSF);
    float un = sqrtf(s2 + uz * uz) + EPSF;
    float u0 = nj0 / un, u1 = nj1 / un, u2 = uz / un;
    float v0 = u1 * nj2 - u2 * nj1;
    float v1 = u2 * nj0 - u0 * nj2;
    float v2 = u0 * nj1 - u1 * nj0;
    float r0 = u0 * x0 + v0 * x1 + nj0 * x2;
    float r1 = u1 * x0 + v1 * x1 + nj1 * x2;
    float r2 = u2 * x0 + v2 * x1 + nj2 * x2;

    float ta[3], tb[3], tc[3];
    ta[0] = u0 * r0 + u1 * r1;   tb[0] = u1 * r0 - u0 * r1;   tc[0] = u2 * r2;
    ta[1] = v0 * r0 + v1 * r1;   tb[1] = v1 * r0 - v0 * r1;   tc[1] = v2 * r2;
    ta[2] = nj0 * r0 + nj1 * r1; tb[2] = nj1 * r0 - nj0 * r1; tc[2] = nj2 * r2;

    size_t rb = ((size_t)b_loc * 3072 + n) * 768 + e;
    #pragma unroll
    for (int i = 0; i < 3; ++i) {
        size_t r = rb + (size_t)i * 1024 * 768;
        T[r]       = (_Float16)ta[i];
        T[r + 256] = (_Float16)tb[i];
        T[r + 512] = (_Float16)tc[i];
    }
}

// ---------------------------------------------------------------------------
// gemm1: per b, Y[c][f] = sum_r M[f][r] * T[c][r], single-pass fp16 MFMA.
// 128f x 128c tile, 4 waves (2x2), K=768, BK=64 (128-B LDS rows, full 8-slot
// XOR swizzle -> conflict-free), double-buffered global_load_lds.
// grid: nb*48.
// ---------------------------------------------------------------------------
__global__ __launch_bounds__(256) void gemm1_kernel(
    const _Float16* __restrict__ Mh, const _Float16* __restrict__ T,
    _Float16* __restrict__ Y)
{
    __shared__ char lds[65536];
    int tid = threadIdx.x;
    int bid = blockIdx.x;
    int b   = bid / 48;
    int rt  = bid % 48;
    int f0  = (rt / 24) * 128;
    int c0  = (rt % 24) * 128;
    size_t bC    = (size_t)b * 3072;
    size_t Tbase = (bC + c0) * 768;

    auto stage = [&](int buf, int kt) {
        char* la = lds + buf * 32768;     // A tile: 128 rows x 128 B = 16 KB
        char* lb = la + 16384;            // B tile: 128 rows x 128 B = 16 KB
        int k0 = kt * 64;
        int wv = (tid >> 6) * 1024;
        #pragma unroll
        for (int h = 0; h < 4; ++h) {
            int m = h * 256 + tid;
            int row = m >> 3, slot = m & 7;
            unsigned sw = (slot * 16) ^ ((row & 7) << 4);
            size_t goA = ((size_t)(f0 + row) * 768 + k0) * 2 + sw;
            size_t goB = (Tbase + (size_t)row * 768 + k0) * 2 + sw;
            glds16((const char*)Mh + goA, la + h * 4096 + wv);
            glds16((const char*)T  + goB, lb + h * 4096 + wv);
        }
    };

    int l = tid & 63, lr = l & 15, lq = l >> 4;
    int w = tid >> 6, wf = w >> 1, wc = w & 1;

    f32x4 acc[4][4] = {};
    stage(0, 0);
    __syncthreads();

    for (int kt = 0; kt < 12; ++kt) {
        int cur = kt & 1;
        if (kt < 11) stage(cur ^ 1, kt + 1);
        const char* la = lds + cur * 32768;
        const char* lb = la + 16384;
        #pragma unroll
        for (int kk = 0; kk < 2; ++kk) {
            half8 af[4], bf[4];
            #pragma unroll
            for (int m = 0; m < 4; ++m) {
                int R = wf * 64 + m * 16 + lr;
                af[m] = *(const half8*)(la + R * 128 + (((kk * 4 + lq) * 16) ^ ((R & 7) << 4)));
            }
            #pragma unroll
            for (int n = 0; n < 4; ++n) {
                int R = wc * 64 + n * 16 + lr;
                bf[n] = *(const half8*)(lb + R * 128 + (((kk * 4 + lq) * 16) ^ ((R & 7) << 4)));
            }
            #pragma unroll
            for (int m = 0; m < 4; ++m)
                #pragma unroll
                for (int n = 0; n < 4; ++n)
                    acc[m][n] = __builtin_amdgcn_mfma_f32_16x16x32_f16(af[m], bf[n], acc[m][n], 0, 0, 0);
        }
        __syncthreads();
    }

    // D: row=f (lq*4+reg), col=c (lr) -> store Y[c][f] fp16 (8 B/lane)
    #pragma unroll
    for (int n = 0; n < 4; ++n) {
        int c = c0 + wc * 64 + n * 16 + lr;
        size_t rowb = (bC + c) * 256;
        #pragma unroll
        for (int m = 0; m < 4; ++m) {
            int fb = f0 + wf * 64 + m * 16 + lq * 4;
            f32x4 v = acc[m][n];
            half4v p;
            p.x = (_Float16)v[0]; p.y = (_Float16)v[1];
            p.z = (_Float16)v[2]; p.w = (_Float16)v[3];
            *(half4v*)(Y + rowb + fb) = p;
        }
    }
}

// ---------------------------------------------------------------------------
// gemm2: per b, D[c][g] = sum_f Y[c][f] * W[g][f], single-pass fp16; epilogue
// = VN leaky relu in f32.  Block tile 192c (3i x 64n) x 64g, 4 waves
// (2 n-halves x 2 g-halves), K=256, BK=64 -> 4 kt.  grid: nb*64.
// ---------------------------------------------------------------------------
__global__ __launch_bounds__(256) void gemm2_kernel(
    const _Float16* __restrict__ Wh, const _Float16* __restrict__ Y,
    float* __restrict__ out, int b_off)
{
    __shared__ char lds[65536];
    int tid = threadIdx.x;
    int bid = blockIdx.x;
    int b   = bid / 64;           // chunk-local b
    int rt  = bid % 64;
    int g0  = (rt >> 4) * 64;
    int n0  = (rt & 15) * 64;
    size_t bC = (size_t)b * 3072;

    auto stage = [&](int buf, int kt) {
        char* la = lds + buf * 32768;   // A = Y tile: 192 rows x 128 B = 24 KB
        char* lb = la + 24576;          // B = W tile:  64 rows x 128 B =  8 KB
        int k0 = kt * 64;
        int wv = (tid >> 6) * 1024;
        #pragma unroll
        for (int h = 0; h < 6; ++h) {
            int m = h * 256 + tid;
            int row = m >> 3, slot = m & 7;
            int cg = (row >> 6) * 1024 + n0 + (row & 63);
            unsigned sw = (slot * 16) ^ ((row & 7) << 4);
            size_t go = ((bC + cg) * 256 + k0) * 2 + sw;
            glds16((const char*)Y + go, la + h * 4096 + wv);
        }
        #pragma unroll
        for (int h = 0; h < 2; ++h) {
            int m = h * 256 + tid;
            int row = m >> 3, slot = m & 7;
            unsigned sw = (slot * 16) ^ ((row & 7) << 4);
            size_t go = ((size_t)(g0 + row) * 256 + k0) * 2 + sw;
            glds16((const char*)Wh + go, lb + h * 4096 + wv);
        }
    };

    int l = tid & 63, lr = l & 15, lq = l >> 4;
    int w = tid >> 6, wn = w & 1, wg = w >> 1;

    f32x4 acc[3][2][2] = {};
    stage(0, 0);
    __syncthreads();

    for (int kt = 0; kt < 4; ++kt) {
        int cur = kt & 1;
        if (kt < 3) stage(cur ^ 1, kt + 1);
        const char* la = lds + cur * 32768;
        const char* lb = la + 24576;
        #pragma unroll
        for (int kk = 0; kk < 2; ++kk) {
            half8 af[3][2], bg[2];
            #pragma unroll
            for (int i = 0; i < 3; ++i)
                #pragma unroll
                for (int nc = 0; nc < 2; ++nc) {
                    int R = i * 64 + wn * 32 + nc * 16 + lr;
                    af[i][nc] = *(const half8*)(la + R * 128 + (((kk * 4 + lq) * 16) ^ ((R & 7) << 4)));
                }
            #pragma unroll
            for (int gf = 0; gf < 2; ++gf) {
                int R = wg * 32 + gf * 16 + lr;
                bg[gf] = *(const half8*)(lb + R * 128 + (((kk * 4 + lq) * 16) ^ ((R & 7) << 4)));
            }
            #pragma unroll
            for (int i = 0; i < 3; ++i)
                #pragma unroll
                for (int nc = 0; nc < 2; ++nc)
                    #pragma unroll
                    for (int gf = 0; gf < 2; ++gf)
                        acc[i][nc][gf] = __builtin_amdgcn_mfma_f32_16x16x32_f16(af[i][nc], bg[gf], acc[i][nc][gf], 0, 0, 0);
        }
        __syncthreads();
    }

    // epilogue; D: row=c (n = nb+reg at fixed i), col=g (lr)
    int b_g = b_off + b;
    #pragma unroll
    for (int nc = 0; nc < 2; ++nc)
        #pragma unroll
        for (int gf = 0; gf < 2; ++gf) {
            int g  = g0 + wg * 32 + gf * 16 + lr;
            int nb = n0 + wn * 32 + nc * 16 + lq * 4;
            float x[3][4];
            #pragma unroll
            for (int i = 0; i < 3; ++i)
                #pragma unroll
                for (int r = 0; r < 4; ++r)
                    x[i][r] = (float)Y[(bC + i * 1024 + nb + r) * 256 + g];
            f32x4 o[3];
            #pragma unroll
            for (int r = 0; r < 4; ++r) {
                float d0 = acc[0][nc][gf][r], d1 = acc[1][nc][gf][r], d2 = acc[2][nc][gf][r];
                float dot = x[0][r] * d0 + x[1][r] * d1 + x[2][r] * d2;
                float dn  = d0 * d0 + d1 * d1 + d2 * d2;
                float sc  = dot / (dn + EPSF);
                bool pos  = dot >= 0.0f;
                float l0 = pos ? x[0][r] : fmaf(-sc, d0, x[0][r]);
                float l1 = pos ? x[1][r] : fmaf(-sc, d1, x[1][r]);
                float l2 = pos ? x[2][r] : fmaf(-sc, d2, x[2][r]);
                o[0][r] = fmaf(0.8f, l0, 0.2f * x[0][r]);
                o[1][r] = fmaf(0.8f, l1, 0.2f * x[1][r]);
                o[2][r] = fmaf(0.8f, l2, 0.2f * x[2][r]);
            }
            #pragma unroll
            for (int i = 0; i < 3; ++i)
                *(f32x4*)(out + ((size_t)(b_g * 256 + g) * 3 + i) * 1024 + nb) = o[i];
        }
}

extern "C" void kernel_launch(void* const* d_in, const int* in_sizes, int n_in,
                              void* d_out, int out_size, void* d_ws, size_t ws_size,
                              hipStream_t stream)
{
    const float* X  = (const float*)d_in[0];
    const float* J  = (const float*)d_in[1];
    const float* A  = (const float*)d_in[2];
    const float* Bw = (const float*)d_in[3];
    const float* Cw = (const float*)d_in[4];
    const float* W  = (const float*)d_in[5];
    float* out = (float*)d_out;

    char* ws = (char*)d_ws;
    _Float16* Mh = (_Float16*)ws;                       // 256*768*2 = 393216
    _Float16* Wh = (_Float16*)(ws + 393216);            // 256*256*2 = 131072
    char* dyn = ws + 524288;

    hipLaunchKernelGGL(prep_kernel, dim3(256), dim3(256), 0, stream,
                       A, Bw, Cw, W, Mh, Wh);

    auto need = [](int nb) {
        return (size_t)524288 + (size_t)nb * 3072 * 768 * 2
                              + (size_t)nb * 3072 * 256 * 2;
    };
    int nb = (ws_size >= need(16)) ? 16 : (ws_size >= need(8)) ? 8 : 4;
    size_t TT = (size_t)nb * 3072 * 768 * 2;
    _Float16* T = (_Float16*)dyn;
    _Float16* Y = (_Float16*)(dyn + TT);

    for (int b0 = 0; b0 < 16; b0 += nb) {
        hipLaunchKernelGGL(tgen_kernel,  dim3(nb * 1024), dim3(256), 0, stream,
                           X, J, T, b0);
        hipLaunchKernelGGL(gemm1_kernel, dim3(nb * 48),   dim3(256), 0, stream,
                           Mh, T, Y);
        hipLaunchKernelGGL(gemm2_kernel, dim3(nb * 64),   dim3(256), 0, stream,
                           Wh, Y, out, b0);
    }
}

// Round 5
// 67.300 us; speedup vs baseline: 11.9073x; 1.3245x over previous
//
#include <hip/hip_runtime.h>

typedef __attribute__((ext_vector_type(8))) _Float16 half8;
typedef __attribute__((ext_vector_type(4))) _Float16 half4v;
typedef __attribute__((ext_vector_type(4))) float f32x4;
typedef float f32x4u __attribute__((ext_vector_type(4), aligned(4)));
typedef float f32x2u __attribute__((ext_vector_type(2), aligned(4)));

#define EPSF 1e-6f

__device__ __forceinline__ void glds16(const void* g, void* l) {
    __builtin_amdgcn_global_load_lds(
        (const __attribute__((address_space(1))) unsigned*)g,
        (__attribute__((address_space(3))) unsigned*)l, 16, 0, 0);
}
__device__ __forceinline__ unsigned short h2u(_Float16 h) {
    union { _Float16 h; unsigned short u; } c; c.h = h; return c.u;
}

// ---------------------------------------------------------------------------
// prep: Mh[f][768] = fp16 of stacked [A|Bw|Cw] (K-contig); Wh[g][256] = fp16(W).
// ---------------------------------------------------------------------------
__global__ __launch_bounds__(256) void prep_kernel(
    const float* __restrict__ A, const float* __restrict__ Bw,
    const float* __restrict__ Cw, const float* __restrict__ W,
    _Float16* __restrict__ Mh, _Float16* __restrict__ Wh)
{
    int f = blockIdx.x, e = threadIdx.x;
    Mh[f * 768 + e]       = (_Float16)A[f * 256 + e];
    Mh[f * 768 + 256 + e] = (_Float16)Bw[f * 256 + e];
    Mh[f * 768 + 512 + e] = (_Float16)Cw[f * 256 + e];
    Wh[f * 256 + e]       = (_Float16)W[f * 256 + e];
}

// ---------------------------------------------------------------------------
// fused1: basis+terms (VALU, in-LDS) fused with GEMM1 (MFMA).
// Block: b x 32-n tile; output Y[c=(3i x 32n)][all 256 f], K=768.
// 512 thr / 8 waves = 2 wc (48 c) x 4 wf (64 f); wave tile 48x64, 12 MFMA/kstep.
// Per e-block(32): T phase (2 pts/thread, 9 fp16 each -> 80B-pitch T-LDS,
// conflict-free reads) then 3 t-steps with glds16-dbuf'd M slices.
// LDS: A 2x16K | T 288 rows x 80 B = 55808 B. grid 512 = 2 blocks/CU.
// ---------------------------------------------------------------------------
__global__ __launch_bounds__(512, 4) void fused1_kernel(
    const float* __restrict__ X, const float* __restrict__ Jp,
    const _Float16* __restrict__ Mh, _Float16* __restrict__ Y)
{
    __shared__ char lds[55808];
    const int T_OFF = 32768;
    int tid = threadIdx.x;
    int b  = blockIdx.x >> 5;
    int n0 = (blockIdx.x & 31) * 32;

    auto stageA = [&](int buf, int kt) {
        int eb = kt / 3, t = kt % 3;
        int k0 = t * 256 + eb * 32;
        #pragma unroll
        for (int h = 0; h < 2; ++h) {
            int u = h * 512 + tid;
            int row = u >> 2, slot = u & 3;
            size_t go = ((size_t)row * 768 + k0) * 2 + ((slot * 16) ^ ((row & 3) << 4));
            glds16((const char*)Mh + go, lds + buf * 16384 + u * 16);
        }
    };

    int l = tid & 63, lr = l & 15, lq = l >> 4;
    int w = tid >> 6, wc = w & 1, wf = w >> 1;      // wc: c-half, wf: f-quarter
    int nl = tid >> 4, ep = tid & 15;               // T-phase point mapping

    f32x4 acc[3][4] = {};
    stageA(0, 0);

    for (int eb = 0; eb < 8; ++eb) {
        __syncthreads();                            // prev reads done; A(kt) arrived
        // ---- T phase: 2 points (e = eb*32 + 2ep, +1) at row n0+nl ----
        {
            size_t pbase = ((size_t)((b * 1024 + n0 + nl) * 256) + eb * 32 + 2 * ep) * 3;
            f32x4u xa = *(const f32x4u*)(X + pbase);
            f32x2u xb = *(const f32x2u*)(X + pbase + 4);
            f32x4u ja = *(const f32x4u*)(Jp + pbase);
            f32x2u jb = *(const f32x2u*)(Jp + pbase + 4);
            float xs[6] = { xa[0], xa[1], xa[2], xa[3], xb[0], xb[1] };
            float js[6] = { ja[0], ja[1], ja[2], ja[3], jb[0], jb[1] };
            unsigned short hv[2][9];
            #pragma unroll
            for (int p = 0; p < 2; ++p) {
                float x0 = xs[3*p], x1 = xs[3*p+1], x2 = xs[3*p+2];
                float j0 = js[3*p], j1 = js[3*p+1], j2 = js[3*p+2];
                float jj  = j0*j0 + j1*j1 + j2*j2;
                float rn  = __builtin_amdgcn_rcpf(__builtin_amdgcn_sqrtf(jj) + EPSF);
                float nj0 = j0*rn, nj1 = j1*rn, nj2 = j2*rn;
                float s2  = nj0*nj0 + nj1*nj1;
                float uz  = -s2 * __builtin_amdgcn_rcpf(nj2 + EPSF);
                float ru  = __builtin_amdgcn_rcpf(__builtin_amdgcn_sqrtf(s2 + uz*uz) + EPSF);
                float u0 = nj0*ru, u1 = nj1*ru, u2 = uz*ru;
                float v0 = u1*nj2 - u2*nj1;
                float v1 = u2*nj0 - u0*nj2;
                float v2 = u0*nj1 - u1*nj0;
                float r0 = u0*x0 + v0*x1 + nj0*x2;
                float r1 = u1*x0 + v1*x1 + nj1*x2;
                float r2 = u2*x0 + v2*x1 + nj2*x2;
                hv[p][0] = h2u((_Float16)(u0*r0 + u1*r1));    // t=0 (A), i=0
                hv[p][1] = h2u((_Float16)(v0*r0 + v1*r1));    // i=1
                hv[p][2] = h2u((_Float16)(nj0*r0 + nj1*r1));  // i=2
                hv[p][3] = h2u((_Float16)(u1*r0 - u0*r1));    // t=1 (Bw)
                hv[p][4] = h2u((_Float16)(v1*r0 - v0*r1));
                hv[p][5] = h2u((_Float16)(nj1*r0 - nj0*r1));
                hv[p][6] = h2u((_Float16)(u2*r2));            // t=2 (Cw)
                hv[p][7] = h2u((_Float16)(v2*r2));
                hv[p][8] = h2u((_Float16)(nj2*r2));
            }
            #pragma unroll
            for (int s = 0; s < 9; ++s) {
                int t = s / 3, i = s % 3;
                unsigned pk = (unsigned)hv[0][s] | ((unsigned)hv[1][s] << 16);
                *(unsigned*)(lds + T_OFF + ((t * 96 + i * 32 + nl) * 80) + ep * 4) = pk;
            }
        }
        __syncthreads();                            // T visible
        // ---- 3 MFMA k-steps (t = 0..2) ----
        #pragma unroll
        for (int t = 0; t < 3; ++t) {
            int kt = eb * 3 + t, buf = kt & 1;
            if (kt < 23) stageA(buf ^ 1, kt + 1);
            const char* la = lds + buf * 16384;
            half8 af[4], bf[3];
            #pragma unroll
            for (int mi = 0; mi < 4; ++mi) {
                int f = wf * 64 + mi * 16 + lr;
                af[mi] = *(const half8*)(la + f * 64 + ((lq * 16) ^ ((f & 3) << 4)));
            }
            #pragma unroll
            for (int bi = 0; bi < 3; ++bi) {
                int cr = wc * 48 + bi * 16 + lr;
                bf[bi] = *(const half8*)(lds + T_OFF + (t * 96 + cr) * 80 + lq * 16);
            }
            #pragma unroll
            for (int bi = 0; bi < 3; ++bi)
                #pragma unroll
                for (int mi = 0; mi < 4; ++mi)
                    acc[bi][mi] = __builtin_amdgcn_mfma_f32_16x16x32_f16(af[mi], bf[bi], acc[bi][mi], 0, 0, 0);
            if (t < 2) __syncthreads();
        }
    }

    // epilogue: D row=f (lq*4+reg), col=c (lr) -> Y[c][f] fp16
    #pragma unroll
    for (int bi = 0; bi < 3; ++bi) {
        int cr = wc * 48 + bi * 16 + lr;
        int i = cr >> 5, nl2 = cr & 31;
        size_t rowb = ((size_t)b * 3072 + i * 1024 + n0 + nl2) * 256;
        #pragma unroll
        for (int mi = 0; mi < 4; ++mi) {
            int fb = wf * 64 + mi * 16 + lq * 4;
            f32x4 v = acc[bi][mi];
            half4v p;
            p.x = (_Float16)v[0]; p.y = (_Float16)v[1];
            p.z = (_Float16)v[2]; p.w = (_Float16)v[3];
            *(half4v*)(Y + rowb + fb) = p;
        }
    }
}

// ---------------------------------------------------------------------------
// gemm2: per b, D[c][g] = sum_f Y[c][f] * W[g][f], single-pass fp16; epilogue
// = VN leaky relu in f32.  Block tile 192c (3i x 64n) x 64g, 4 waves,
// K=256, BK=64 -> 4 kt.  grid: 16*64.
// ---------------------------------------------------------------------------
__global__ __launch_bounds__(256) void gemm2_kernel(
    const _Float16* __restrict__ Wh, const _Float16* __restrict__ Y,
    float* __restrict__ out, int b_off)
{
    __shared__ char lds[65536];
    int tid = threadIdx.x;
    int bid = blockIdx.x;
    int b   = bid / 64;
    int rt  = bid % 64;
    int g0  = (rt >> 4) * 64;
    int n0  = (rt & 15) * 64;
    size_t bC = (size_t)b * 3072;

    auto stage = [&](int buf, int kt) {
        char* la = lds + buf * 32768;   // A = Y tile: 192 rows x 128 B = 24 KB
        char* lb = la + 24576;          // B = W tile:  64 rows x 128 B =  8 KB
        int k0 = kt * 64;
        int wv = (tid >> 6) * 1024;
        #pragma unroll
        for (int h = 0; h < 6; ++h) {
            int m = h * 256 + tid;
            int row = m >> 3, slot = m & 7;
            int cg = (row >> 6) * 1024 + n0 + (row & 63);
            unsigned sw = (slot * 16) ^ ((row & 7) << 4);
            size_t go = ((bC + cg) * 256 + k0) * 2 + sw;
            glds16((const char*)Y + go, la + h * 4096 + wv);
        }
        #pragma unroll
        for (int h = 0; h < 2; ++h) {
            int m = h * 256 + tid;
            int row = m >> 3, slot = m & 7;
            unsigned sw = (slot * 16) ^ ((row & 7) << 4);
            size_t go = ((size_t)(g0 + row) * 256 + k0) * 2 + sw;
            glds16((const char*)Wh + go, lb + h * 4096 + wv);
        }
    };

    int l = tid & 63, lr = l & 15, lq = l >> 4;
    int w = tid >> 6, wn = w & 1, wg = w >> 1;

    f32x4 acc[3][2][2] = {};
    stage(0, 0);
    __syncthreads();

    for (int kt = 0; kt < 4; ++kt) {
        int cur = kt & 1;
        if (kt < 3) stage(cur ^ 1, kt + 1);
        const char* la = lds + cur * 32768;
        const char* lb = la + 24576;
        #pragma unroll
        for (int kk = 0; kk < 2; ++kk) {
            half8 af[3][2], bg[2];
            #pragma unroll
            for (int i = 0; i < 3; ++i)
                #pragma unroll
                for (int nc = 0; nc < 2; ++nc) {
                    int R = i * 64 + wn * 32 + nc * 16 + lr;
                    af[i][nc] = *(const half8*)(la + R * 128 + (((kk * 4 + lq) * 16) ^ ((R & 7) << 4)));
                }
            #pragma unroll
            for (int gf = 0; gf < 2; ++gf) {
                int R = wg * 32 + gf * 16 + lr;
                bg[gf] = *(const half8*)(lb + R * 128 + (((kk * 4 + lq) * 16) ^ ((R & 7) << 4)));
            }
            #pragma unroll
            for (int i = 0; i < 3; ++i)
                #pragma unroll
                for (int nc = 0; nc < 2; ++nc)
                    #pragma unroll
                    for (int gf = 0; gf < 2; ++gf)
                        acc[i][nc][gf] = __builtin_amdgcn_mfma_f32_16x16x32_f16(af[i][nc], bg[gf], acc[i][nc][gf], 0, 0, 0);
        }
        __syncthreads();
    }

    int b_g = b_off + b;
    #pragma unroll
    for (int nc = 0; nc < 2; ++nc)
        #pragma unroll
        for (int gf = 0; gf < 2; ++gf) {
            int g  = g0 + wg * 32 + gf * 16 + lr;
            int nb = n0 + wn * 32 + nc * 16 + lq * 4;
            float x[3][4];
            #pragma unroll
            for (int i = 0; i < 3; ++i)
                #pragma unroll
                for (int r = 0; r < 4; ++r)
                    x[i][r] = (float)Y[(bC + i * 1024 + nb + r) * 256 + g];
            f32x4 o[3];
            #pragma unroll
            for (int r = 0; r < 4; ++r) {
                float d0 = acc[0][nc][gf][r], d1 = acc[1][nc][gf][r], d2 = acc[2][nc][gf][r];
                float dot = x[0][r] * d0 + x[1][r] * d1 + x[2][r] * d2;
                float dn  = d0 * d0 + d1 * d1 + d2 * d2;
                float sc  = dot / (dn + EPSF);
                bool pos  = dot >= 0.0f;
                float l0 = pos ? x[0][r] : fmaf(-sc, d0, x[0][r]);
                float l1 = pos ? x[1][r] : fmaf(-sc, d1, x[1][r]);
                float l2 = pos ? x[2][r] : fmaf(-sc, d2, x[2][r]);
                o[0][r] = fmaf(0.8f, l0, 0.2f * x[0][r]);
                o[1][r] = fmaf(0.8f, l1, 0.2f * x[1][r]);
                o[2][r] = fmaf(0.8f, l2, 0.2f * x[2][r]);
            }
            #pragma unroll
            for (int i = 0; i < 3; ++i)
                *(f32x4*)(out + ((size_t)(b_g * 256 + g) * 3 + i) * 1024 + nb) = o[i];
        }
}

extern "C" void kernel_launch(void* const* d_in, const int* in_sizes, int n_in,
                              void* d_out, int out_size, void* d_ws, size_t ws_size,
                              hipStream_t stream)
{
    const float* X  = (const float*)d_in[0];
    const float* J  = (const float*)d_in[1];
    const float* A  = (const float*)d_in[2];
    const float* Bw = (const float*)d_in[3];
    const float* Cw = (const float*)d_in[4];
    const float* W  = (const float*)d_in[5];
    float* out = (float*)d_out;

    char* ws = (char*)d_ws;
    _Float16* Mh = (_Float16*)ws;                       // 256*768*2 = 393216
    _Float16* Wh = (_Float16*)(ws + 393216);            // 256*256*2 = 131072
    _Float16* Y  = (_Float16*)(ws + 524288);            // 16*3072*256*2 = 25.2 MB

    hipLaunchKernelGGL(prep_kernel,   dim3(256),  dim3(256), 0, stream,
                       A, Bw, Cw, W, Mh, Wh);
    hipLaunchKernelGGL(fused1_kernel, dim3(512),  dim3(512), 0, stream,
                       X, J, Mh, Y);
    hipLaunchKernelGGL(gemm2_kernel,  dim3(1024), dim3(256), 0, stream,
                       Wh, Y, out, 0);
}